// Round 13
// baseline (235.036 us; speedup 1.0000x reference)
//
#include <hip/hip_runtime.h>

#define NUM_SEGS 1024
#define CHUNK_LOG 13
#define CHUNK (1 << CHUNK_LOG)   // 8192 elements per chunk
#define SUBCH 2                  // chunks per block (block span = 16384)
#define SUPER (CHUNK * SUBCH)
#define BLK 256                  // 4 waves/block; grid 1024 -> 4 blocks/CU
#define NWAVE (BLK / 64)
#define STAGE 256                // elems per stage per wave (1KB/array = 1 load)
#define NSTAGE 16                // 16 stages x 256 = 4096 elems per wave
#define SEGBLK 256
#define SEGWAVES (SEGBLK / 64)

#define GLOAD_LDS(gptr, lptr)                                                  \
    __builtin_amdgcn_global_load_lds(                                          \
        (const __attribute__((address_space(1))) void*)(gptr),                 \
        (__attribute__((address_space(3))) void*)(lptr), 16, 0, 0)

__device__ __forceinline__ float waveReduceSumF(float v) {
#pragma unroll
    for (int off = 32; off > 0; off >>= 1) v += __shfl_down(v, off, 64);
    return v;
}
__device__ __forceinline__ double waveReduceSumD(double v) {
#pragma unroll
    for (int off = 32; off > 0; off >>= 1) v += __shfl_down(v, off, 64);
    return v;
}
__device__ __forceinline__ unsigned waveReduceSumU(unsigned v) {
#pragma unroll
    for (int off = 32; off > 0; off >>= 1) v += __shfl_down(v, off, 64);
    return v;
}
__device__ __forceinline__ int waveReduceMaxI(int v) {
#pragma unroll
    for (int off = 32; off > 0; off >>= 1) {
        const int o = __shfl_down(v, off, 64);
        v = o > v ? o : v;
    }
    return v;
}

// ---------------- pass 1: global_load_lds staged streaming -------------------
// MLP without VGPRs: each wave double-buffers 256-elem slices of the 3 arrays
// in its PRIVATE LDS region via global_load_lds (3 x 1KB loads per stage),
// issuing stage j+1 before consuming stage j. Per-wave counted vmcnt(3) +
// sched_barrier(0) (rule #18) -- no block barriers in the hot loop, nothing
// for the register allocator to collapse. 16 waves/CU x ~6KB in flight.
__global__ __launch_bounds__(BLK, 4) void pass1_kernel(
    const float* __restrict__ outs, const int* __restrict__ te,
    const int* __restrict__ tt, int N, int nChunks,
    float* __restrict__ csums, unsigned short* __restrict__ hist_part,
    float* __restrict__ e1part, unsigned* __restrict__ obspart) {
    __shared__ unsigned hist[NUM_SEGS];                 // 4 KB
    __shared__ float stgO[NWAVE][2][STAGE];             // 8 KB
    __shared__ int stgE[NWAVE][2][STAGE];               // 8 KB
    __shared__ int stgT[NWAVE][2][STAGE];               // 8 KB
    __shared__ float redK[SUBCH][NWAVE];
    __shared__ float redF[NWAVE];
    __shared__ unsigned redU[NWAVE];

    const int tid = (int)threadIdx.x;
    const int lane = tid & 63;
    const int wid = tid >> 6;
    const int bid = (int)blockIdx.x;
    const int superBase = bid * SUPER;

    for (int t = tid; t < NUM_SEGS; t += BLK) hist[t] = 0u;
    if (tid < SUBCH * NWAVE) redK[tid >> 2][tid & 3] = 0.f;
    __syncthreads();

    float sumExp = 0.f;   // this wave's 4096 elems lie in ONE chunk (wid>>1)
    float sumOE = 0.f;
    unsigned cntE = 0u;

    if (superBase + SUPER <= N) {
        const int wbase = superBase + (wid << 12);  // wave's 4096-elem region
        const int l4 = lane << 2;

#define ISSUE_STAGE(j, buf)                                                    \
    do {                                                                       \
        const int _sb = wbase + (j) * STAGE;                                   \
        GLOAD_LDS(outs + _sb + l4, &stgO[wid][buf][0]);                        \
        GLOAD_LDS(te + _sb + l4, &stgE[wid][buf][0]);                          \
        GLOAD_LDS(tt + _sb + l4, &stgT[wid][buf][0]);                          \
    } while (0)

        ISSUE_STAGE(0, 0);
#pragma unroll
        for (int j = 0; j < NSTAGE; ++j) {
            const int buf = j & 1;  // compile-time (unrolled)
            if (j + 1 < NSTAGE) ISSUE_STAGE(j + 1, (j + 1) & 1);
            __builtin_amdgcn_sched_barrier(0);
            if (j + 1 < NSTAGE) asm volatile("s_waitcnt vmcnt(3)");
            else                asm volatile("s_waitcnt vmcnt(0)");
            __builtin_amdgcn_sched_barrier(0);  // rule #18: no hoist past wait
            {
                const float4 o = *reinterpret_cast<const float4*>(&stgO[wid][buf][l4]);
                const int4 ev = *reinterpret_cast<const int4*>(&stgE[wid][buf][l4]);
                const int4 sv = *reinterpret_cast<const int4*>(&stgT[wid][buf][l4]);
                sumExp += (__expf(o.x) + __expf(o.y)) +
                          (__expf(o.z) + __expf(o.w));
                const int s0 = sv.x < 0 ? -sv.x : sv.x;
                const int s1 = sv.y < 0 ? -sv.y : sv.y;
                const int s2 = sv.z < 0 ? -sv.z : sv.z;
                const int s3 = sv.w < 0 ? -sv.w : sv.w;
                if (ev.x > 0) { cntE++; sumOE += o.x; atomicAdd(&hist[s0], 1u); }
                if (ev.y > 0) { cntE++; sumOE += o.y; atomicAdd(&hist[s1], 1u); }
                if (ev.z > 0) { cntE++; sumOE += o.z; atomicAdd(&hist[s2], 1u); }
                if (ev.w > 0) { cntE++; sumOE += o.w; atomicAdd(&hist[s3], 1u); }
            }
        }
#undef ISSUE_STAGE

        // wave's chunk partial: chunk (wid>>1)
        const float w = waveReduceSumF(sumExp);
        if (lane == 0) redK[wid >> 1][wid] = w;
    } else {
        // tail path (not hit for N = 16M)
        for (int k = 0; k < SUBCH; ++k) {
            const int cbase = superBase + k * CHUNK;
            if (cbase >= N) break;
            const int end = (cbase + CHUNK < N) ? cbase + CHUNK : N;
            float s = 0.f;
            for (int i = cbase + tid; i < end; i += BLK) {
                const float o = outs[i];
                const int e = te[i];
                int sg = tt[i]; sg = sg < 0 ? -sg : sg;
                s += __expf(o);
                if (e > 0) { cntE++; sumOE += o; atomicAdd(&hist[sg], 1u); }
            }
            const float w = waveReduceSumF(s);
            if (lane == 0 && w != 0.f) atomicAdd(&redK[k][0], w);  // LDS atomic
        }
    }

    // E-stat wave partials
    {
        const float wOE = waveReduceSumF(sumOE);
        const unsigned wC = waveReduceSumU(cntE);
        if (lane == 0) { redF[wid] = wOE; redU[wid] = wC; }
    }

    __syncthreads();  // hist + redK/redF/redU complete

    // hist -> per-block u16 partials (plain coalesced stores, no atomics)
    for (int t = tid; t < NUM_SEGS; t += BLK)
        hist_part[(size_t)bid * NUM_SEGS + t] = (unsigned short)hist[t];

    if (tid == 0) {
        const int c0 = superBase >> CHUNK_LOG;
#pragma unroll
        for (int k = 0; k < SUBCH; ++k) {
            const int cbase = superBase + k * CHUNK;
            if (cbase < N) {
                float cs = 0.f;
#pragma unroll
                for (int j = 0; j < NWAVE; ++j) cs += redK[k][j];
                csums[c0 + k] = cs;
            }
        }
        float oe = 0.f; unsigned c = 0u;
#pragma unroll
        for (int j = 0; j < NWAVE; ++j) { oe += redF[j]; c += redU[j]; }
        e1part[bid] = oe;
        obspart[bid] = c;
    }
}

// ---------------- pass 2: per-segment work + direct fp32 accumulation to out -
// (byte-identical logic to r10/r11's passing version; nSuper now 1024)
__global__ __launch_bounds__(SEGBLK) void seg_final_kernel(
    const float* __restrict__ outs, const int* __restrict__ tt,
    const float* __restrict__ csums, const unsigned short* __restrict__ hist_part,
    const float* __restrict__ e1part, const unsigned* __restrict__ obspart,
    float* __restrict__ out, int N, int nChunks, int nSuper) {
    __shared__ double redD[SEGWAVES];
    __shared__ float redF[SEGWAVES];
    __shared__ int redI[SEGWAVES];
    __shared__ unsigned redObs[SEGWAVES];
    __shared__ unsigned redCnt[SEGWAVES];
    __shared__ int s_li;
    __shared__ unsigned s_cnt;

    const int t = (int)blockIdx.x;
    const int tid = (int)threadIdx.x;
    const int lane = tid & 63, wid = tid >> 6;

    // Obs partial-sum (kept in redObs; only tid 0 consumes it later)
    {
        unsigned ob = 0u;
        for (int b = tid; b < nSuper; b += SEGBLK) ob += obspart[b];
        ob = waveReduceSumU(ob);
        if (lane == 0) redObs[wid] = ob;
    }

    // block 0: the -loss1/Obs term
    if (t == 0) {
        double p = 0.0;
        for (int b = tid; b < nSuper; b += SEGBLK) p += (double)e1part[b];
        p = waveReduceSumD(p);
        if (lane == 0) redD[wid] = p;
        __syncthreads();
        if (tid == 0) {
            double L1 = 0.0, Obs = 0.0;
#pragma unroll
            for (int j = 0; j < SEGWAVES; ++j) {
                L1 += redD[j];
                Obs += (double)redObs[j];
            }
            atomicAdd(out, (float)(-L1 / Obs));
        }
        __syncthreads();  // redD reused below
    }

    // cnt for this segment: column sum of u16 partials
    {
        unsigned c = 0u;
        for (int b = tid; b < nSuper; b += SEGBLK)
            c += (unsigned)hist_part[(size_t)b * NUM_SEGS + t];
        c = waveReduceSumU(c);
        if (lane == 0) redCnt[wid] = c;
    }
    __syncthreads();
    if (tid == 0) {
        unsigned c = 0u;
#pragma unroll
        for (int j = 0; j < SEGWAVES; ++j) c += redCnt[j];
        s_cnt = c;
    }
    __syncthreads();
    const unsigned cnt = s_cnt;
    if (cnt == 0u) return;  // empty segment contributes 0

    // ---- backward search for the last occurrence of segment t ----
    int c = nChunks - 1;
    int LI = -1;
    for (;;) {
        const int base = c << CHUNK_LOG;
        const int end = (base + CHUNK < N) ? base + CHUNK : N;
        const int span = end - base;
        const int qspan = span & ~3;  // int4-aligned portion
        int li = -1;
        for (int i = base + (tid << 2); i < base + qspan; i += SEGBLK * 4) {
            const int4 sv = *reinterpret_cast<const int4*>(tt + i);
            const int s0 = sv.x < 0 ? -sv.x : sv.x;
            const int s1 = sv.y < 0 ? -sv.y : sv.y;
            const int s2 = sv.z < 0 ? -sv.z : sv.z;
            const int s3 = sv.w < 0 ? -sv.w : sv.w;
            if (s3 == t) li = i + 3;
            else if (s2 == t) li = i + 2;
            else if (s1 == t) li = i + 1;
            else if (s0 == t) li = i;
            // ascending i => later assignment always larger
        }
        for (int i = base + qspan + tid; i < end; i += SEGBLK) {
            int s = tt[i]; s = s < 0 ? -s : s;
            if (s == t && i > li) li = i;
        }
        li = waveReduceMaxI(li);
        if (lane == 0) redI[wid] = li;
        __syncthreads();
        if (tid == 0) {
            int m = redI[0];
#pragma unroll
            for (int j = 1; j < SEGWAVES; ++j) m = redI[j] > m ? redI[j] : m;
            s_li = m;
        }
        __syncthreads();
        LI = s_li;
        if (LI >= 0 || --c < 0) break;
    }
    if (LI < 0) return;

    // fp64 exclusive prefix of chunk sums [0, c)
    {
        double p = 0.0;
        for (int j = tid; j < c; j += SEGBLK) p += (double)csums[j];
        p = waveReduceSumD(p);
        if (lane == 0) redD[wid] = p;
    }

    // fp32 in-chunk exp-sum up to and including LI
    {
        const int base = c << CHUNK_LOG;
        float fs = 0.f;
        for (int i = base + tid; i <= LI; i += SEGBLK) fs += __expf(outs[i]);
        fs = waveReduceSumF(fs);
        if (lane == 0) redF[wid] = fs;
    }
    __syncthreads();
    if (tid == 0) {
        double pre = 0.0, Obs = 0.0;
        float fsum = 0.f;
#pragma unroll
        for (int j = 0; j < SEGWAVES; ++j) {
            pre += redD[j];
            fsum += redF[j];
            Obs += (double)redObs[j];
        }
        double sm = log(pre + (double)fsum);  // monotone cumsum => max at LI
        if (sm < 0.0) sm = 0.0;               // jnp.maximum(..., 0.0)
        atomicAdd(out, (float)(sm * (double)cnt / Obs));
    }
}

extern "C" void kernel_launch(void* const* d_in, const int* in_sizes, int n_in,
                              void* d_out, int out_size, void* d_ws, size_t ws_size,
                              hipStream_t stream) {
    const float* outs = (const float*)d_in[0];
    const int* te = (const int*)d_in[1];
    const int* tt = (const int*)d_in[2];
    const int N = in_sizes[0];
    float* out = (float*)d_out;

    const int nChunks = (N + CHUNK - 1) / CHUNK;
    const int nSuper = (N + SUPER - 1) / SUPER;

    // workspace layout: everything is written by pass1 before seg_final reads
    // it -- no initialization dispatch. ~2.1 MB at N=16M.
    char* ws = (char*)d_ws;
    float* d_csums = (float*)ws;                                     // nChunks f32
    unsigned short* d_histp = (unsigned short*)(d_csums + nChunks);  // nSuper*1024 u16
    float* d_e1 = (float*)(d_histp + (size_t)nSuper * NUM_SEGS);     // nSuper f32
    unsigned* d_obsp = (unsigned*)(d_e1 + nSuper);                   // nSuper u32

    pass1_kernel<<<nSuper, BLK, 0, stream>>>(outs, te, tt, N, nChunks, d_csums,
                                             d_histp, d_e1, d_obsp);
    seg_final_kernel<<<NUM_SEGS, SEGBLK, 0, stream>>>(
        outs, tt, d_csums, d_histp, d_e1, d_obsp, out, N, nChunks, nSuper);
}

// Round 14
// 206.654 us; speedup vs baseline: 1.1373x; 1.1373x over previous
//
#include <hip/hip_runtime.h>

#define NUM_SEGS 1024
#define CHUNK_LOG 13
#define CHUNK (1 << CHUNK_LOG)   // 8192 elements per chunk
#define SUBCH 4                  // chunks per block (superchunk = 32768)
#define SUPER (CHUNK * SUBCH)
#define BLK 1024                 // 16 waves/block; grid 512 -> 2 blocks/CU = 32 waves/CU
#define NWAVE (BLK / 64)
#define NBATCH 8                 // batches/thread (1 float4-triple each)
#define PDEPTH 4                 // software-pipeline depth (r11's verified config)
#define SEGBLK 256
#define SEGWAVES (SEGBLK / 64)

__device__ __forceinline__ float waveReduceSumF(float v) {
#pragma unroll
    for (int off = 32; off > 0; off >>= 1) v += __shfl_down(v, off, 64);
    return v;
}
__device__ __forceinline__ double waveReduceSumD(double v) {
#pragma unroll
    for (int off = 32; off > 0; off >>= 1) v += __shfl_down(v, off, 64);
    return v;
}
__device__ __forceinline__ unsigned waveReduceSumU(unsigned v) {
#pragma unroll
    for (int off = 32; off > 0; off >>= 1) v += __shfl_down(v, off, 64);
    return v;
}
__device__ __forceinline__ int waveReduceMaxI(int v) {
#pragma unroll
    for (int off = 32; off > 0; off >>= 1) {
        const int o = __shfl_down(v, off, 64);
        v = o > v ? o : v;
    }
    return v;
}

// ---------------- pass 1: r11's verified-best configuration ------------------
// 32 waves/CU (BLK=1024, grid 512, 2 blocks/CU), NBATCH=8 batches/thread,
// all outputs plain stores (no init dispatch, no global atomics):
//   csums[c0..c0+3]          : block-reduced chunk exp-sums (block owns chunks)
//   hist_part[bid][0..1023]  : u16 per-segment E-counts (max 32768 fits u16)
//   e1part[bid], obspart[bid]: block E-stat partials
// Measured: 43us, VGPR 24, occ 61%, FETCH 49MB -> 4.5 TB/s effective.
__global__ __launch_bounds__(BLK, 8) void pass1_kernel(
    const float* __restrict__ outs, const int* __restrict__ te,
    const int* __restrict__ tt, int N, int nChunks,
    float* __restrict__ csums, unsigned short* __restrict__ hist_part,
    float* __restrict__ e1part, unsigned* __restrict__ obspart) {
    __shared__ unsigned hist[NUM_SEGS];
    __shared__ float redC[SUBCH][NWAVE];
    __shared__ float redF[NWAVE];
    __shared__ unsigned redU[NWAVE];

    for (int t = threadIdx.x; t < NUM_SEGS; t += BLK) hist[t] = 0u;
    __syncthreads();

    const int lane = threadIdx.x & 63;
    const int wid = threadIdx.x >> 6;
    const int bid = (int)blockIdx.x;
    const int superBase = bid * SUPER;

    float sE[SUBCH] = {0.f, 0.f, 0.f, 0.f};  // batch b -> chunk b>>1 (static)
    float sumOE = 0.f;
    unsigned cntE = 0u;

    if (superBase + SUPER <= N) {
        const int i0 = superBase + ((int)threadIdx.x << 2);
        float4 O[PDEPTH];
        int4 E[PDEPTH], S[PDEPTH];

#define LOADB(b, sl)                                                        \
    do {                                                                    \
        const int _i = i0 + (b) * (BLK * 4);                                \
        O[sl] = *reinterpret_cast<const float4*>(outs + _i);                \
        E[sl] = *reinterpret_cast<const int4*>(te + _i);                    \
        S[sl] = *reinterpret_cast<const int4*>(tt + _i);                    \
    } while (0)

        // prologue: fill the pipeline
#pragma unroll
        for (int b = 0; b < PDEPTH; ++b) LOADB(b, b);

#pragma unroll
        for (int b = 0; b < NBATCH; ++b) {
            if (b + PDEPTH < NBATCH) LOADB(b + PDEPTH, (b + PDEPTH) % PDEPTH);
            __builtin_amdgcn_sched_barrier(0);  // pin issue above consume
            {
                const int sl = b % PDEPTH;  // compile-time (unrolled)
                const float4 o = O[sl];
                const int4 ev = E[sl];
                const int4 sv = S[sl];
                sE[b >> 1] += (__expf(o.x) + __expf(o.y)) +
                              (__expf(o.z) + __expf(o.w));
                const int s0 = sv.x < 0 ? -sv.x : sv.x;
                const int s1 = sv.y < 0 ? -sv.y : sv.y;
                const int s2 = sv.z < 0 ? -sv.z : sv.z;
                const int s3 = sv.w < 0 ? -sv.w : sv.w;
                if (ev.x > 0) { cntE++; sumOE += o.x; atomicAdd(&hist[s0], 1u); }
                if (ev.y > 0) { cntE++; sumOE += o.y; atomicAdd(&hist[s1], 1u); }
                if (ev.z > 0) { cntE++; sumOE += o.z; atomicAdd(&hist[s2], 1u); }
                if (ev.w > 0) { cntE++; sumOE += o.w; atomicAdd(&hist[s3], 1u); }
            }
        }
#undef LOADB

        // per-chunk wave partials -> LDS
#pragma unroll
        for (int k = 0; k < SUBCH; ++k) {
            const float w = waveReduceSumF(sE[k]);
            if (lane == 0) redC[k][wid] = w;
        }
    } else {
        // tail path (not hit for N = 16M); block still owns its chunks
        if (lane == 0) {
#pragma unroll
            for (int k = 0; k < SUBCH; ++k) redC[k][wid] = 0.f;
        }
        for (int k = 0; k < SUBCH; ++k) {
            const int cbase = superBase + k * CHUNK;
            if (cbase >= N) break;
            const int end = (cbase + CHUNK < N) ? cbase + CHUNK : N;
            float s = 0.f;
            for (int i = cbase + (int)threadIdx.x; i < end; i += BLK) {
                const float o = outs[i];
                const int e = te[i];
                int sg = tt[i]; sg = sg < 0 ? -sg : sg;
                s += __expf(o);
                if (e > 0) { cntE++; sumOE += o; atomicAdd(&hist[sg], 1u); }
            }
            const float w = waveReduceSumF(s);
            if (lane == 0) redC[k][wid] = w;
        }
    }

    // E-stat wave partials
    {
        const float wOE = waveReduceSumF(sumOE);
        const unsigned wC = waveReduceSumU(cntE);
        if (lane == 0) { redF[wid] = wOE; redU[wid] = wC; }
    }

    __syncthreads();  // hist + redC/redF/redU complete

    // hist -> per-block u16 partials (plain coalesced stores, no atomics)
    for (int t = threadIdx.x; t < NUM_SEGS; t += BLK)
        hist_part[(size_t)bid * NUM_SEGS + t] = (unsigned short)hist[t];

    if (threadIdx.x == 0) {
        const int c0 = superBase >> CHUNK_LOG;
#pragma unroll
        for (int k = 0; k < SUBCH; ++k) {
            const int cbase = superBase + k * CHUNK;
            if (cbase < N) {
                float cs = 0.f;
#pragma unroll
                for (int j = 0; j < NWAVE; ++j) cs += redC[k][j];
                csums[c0 + k] = cs;
            }
        }
        float oe = 0.f; unsigned c = 0u;
#pragma unroll
        for (int j = 0; j < NWAVE; ++j) { oe += redF[j]; c += redU[j]; }
        e1part[bid] = oe;
        obspart[bid] = c;
    }
}

// ---------------- pass 2: per-segment work + direct fp32 accumulation to out -
// (byte-identical logic to r10/r11's passing version)
__global__ __launch_bounds__(SEGBLK) void seg_final_kernel(
    const float* __restrict__ outs, const int* __restrict__ tt,
    const float* __restrict__ csums, const unsigned short* __restrict__ hist_part,
    const float* __restrict__ e1part, const unsigned* __restrict__ obspart,
    float* __restrict__ out, int N, int nChunks, int nSuper) {
    __shared__ double redD[SEGWAVES];
    __shared__ float redF[SEGWAVES];
    __shared__ int redI[SEGWAVES];
    __shared__ unsigned redObs[SEGWAVES];
    __shared__ unsigned redCnt[SEGWAVES];
    __shared__ int s_li;
    __shared__ unsigned s_cnt;

    const int t = (int)blockIdx.x;
    const int tid = (int)threadIdx.x;
    const int lane = tid & 63, wid = tid >> 6;

    // Obs partial-sum (kept in redObs; only tid 0 consumes it later)
    {
        unsigned ob = 0u;
        for (int b = tid; b < nSuper; b += SEGBLK) ob += obspart[b];
        ob = waveReduceSumU(ob);
        if (lane == 0) redObs[wid] = ob;
    }

    // block 0: the -loss1/Obs term
    if (t == 0) {
        double p = 0.0;
        for (int b = tid; b < nSuper; b += SEGBLK) p += (double)e1part[b];
        p = waveReduceSumD(p);
        if (lane == 0) redD[wid] = p;
        __syncthreads();
        if (tid == 0) {
            double L1 = 0.0, Obs = 0.0;
#pragma unroll
            for (int j = 0; j < SEGWAVES; ++j) {
                L1 += redD[j];
                Obs += (double)redObs[j];
            }
            atomicAdd(out, (float)(-L1 / Obs));
        }
        __syncthreads();  // redD reused below
    }

    // cnt for this segment: column sum of u16 partials
    {
        unsigned c = 0u;
        for (int b = tid; b < nSuper; b += SEGBLK)
            c += (unsigned)hist_part[(size_t)b * NUM_SEGS + t];
        c = waveReduceSumU(c);
        if (lane == 0) redCnt[wid] = c;
    }
    __syncthreads();
    if (tid == 0) {
        unsigned c = 0u;
#pragma unroll
        for (int j = 0; j < SEGWAVES; ++j) c += redCnt[j];
        s_cnt = c;
    }
    __syncthreads();
    const unsigned cnt = s_cnt;
    if (cnt == 0u) return;  // empty segment contributes 0

    // ---- backward search for the last occurrence of segment t ----
    int c = nChunks - 1;
    int LI = -1;
    for (;;) {
        const int base = c << CHUNK_LOG;
        const int end = (base + CHUNK < N) ? base + CHUNK : N;
        const int span = end - base;
        const int qspan = span & ~3;  // int4-aligned portion
        int li = -1;
        for (int i = base + (tid << 2); i < base + qspan; i += SEGBLK * 4) {
            const int4 sv = *reinterpret_cast<const int4*>(tt + i);
            const int s0 = sv.x < 0 ? -sv.x : sv.x;
            const int s1 = sv.y < 0 ? -sv.y : sv.y;
            const int s2 = sv.z < 0 ? -sv.z : sv.z;
            const int s3 = sv.w < 0 ? -sv.w : sv.w;
            if (s3 == t) li = i + 3;
            else if (s2 == t) li = i + 2;
            else if (s1 == t) li = i + 1;
            else if (s0 == t) li = i;
            // ascending i => later assignment always larger
        }
        for (int i = base + qspan + tid; i < end; i += SEGBLK) {
            int s = tt[i]; s = s < 0 ? -s : s;
            if (s == t && i > li) li = i;
        }
        li = waveReduceMaxI(li);
        if (lane == 0) redI[wid] = li;
        __syncthreads();
        if (tid == 0) {
            int m = redI[0];
#pragma unroll
            for (int j = 1; j < SEGWAVES; ++j) m = redI[j] > m ? redI[j] : m;
            s_li = m;
        }
        __syncthreads();
        LI = s_li;
        if (LI >= 0 || --c < 0) break;
    }
    if (LI < 0) return;

    // fp64 exclusive prefix of chunk sums [0, c)
    {
        double p = 0.0;
        for (int j = tid; j < c; j += SEGBLK) p += (double)csums[j];
        p = waveReduceSumD(p);
        if (lane == 0) redD[wid] = p;
    }

    // fp32 in-chunk exp-sum up to and including LI
    {
        const int base = c << CHUNK_LOG;
        float fs = 0.f;
        for (int i = base + tid; i <= LI; i += SEGBLK) fs += __expf(outs[i]);
        fs = waveReduceSumF(fs);
        if (lane == 0) redF[wid] = fs;
    }
    __syncthreads();
    if (tid == 0) {
        double pre = 0.0, Obs = 0.0;
        float fsum = 0.f;
#pragma unroll
        for (int j = 0; j < SEGWAVES; ++j) {
            pre += redD[j];
            fsum += redF[j];
            Obs += (double)redObs[j];
        }
        double sm = log(pre + (double)fsum);  // monotone cumsum => max at LI
        if (sm < 0.0) sm = 0.0;               // jnp.maximum(..., 0.0)
        atomicAdd(out, (float)(sm * (double)cnt / Obs));
    }
}

extern "C" void kernel_launch(void* const* d_in, const int* in_sizes, int n_in,
                              void* d_out, int out_size, void* d_ws, size_t ws_size,
                              hipStream_t stream) {
    const float* outs = (const float*)d_in[0];
    const int* te = (const int*)d_in[1];
    const int* tt = (const int*)d_in[2];
    const int N = in_sizes[0];
    float* out = (float*)d_out;

    const int nChunks = (N + CHUNK - 1) / CHUNK;
    const int nSuper = (N + SUPER - 1) / SUPER;

    // workspace layout: everything is written by pass1 before seg_final reads
    // it -- no initialization dispatch, no poisoned-state hazard.
    char* ws = (char*)d_ws;
    float* d_csums = (float*)ws;                                   // nChunks f32
    unsigned short* d_histp = (unsigned short*)(d_csums + nChunks);  // nSuper*1024 u16
    float* d_e1 = (float*)(d_histp + (size_t)nSuper * NUM_SEGS);   // nSuper f32
    unsigned* d_obsp = (unsigned*)(d_e1 + nSuper);                 // nSuper u32

    pass1_kernel<<<nSuper, BLK, 0, stream>>>(outs, te, tt, N, nChunks, d_csums,
                                             d_histp, d_e1, d_obsp);
    seg_final_kernel<<<NUM_SEGS, SEGBLK, 0, stream>>>(
        outs, tt, d_csums, d_histp, d_e1, d_obsp, out, N, nChunks, nSuper);
}